// Round 1
// baseline (624.893 us; speedup 1.0000x reference)
//
#include <hip/hip_runtime.h>

typedef unsigned short ushort_t;
typedef short s8v __attribute__((ext_vector_type(8)));
typedef unsigned short ushort8 __attribute__((ext_vector_type(8)));
typedef float floatx4 __attribute__((ext_vector_type(4)));

#define MFMA16(a, b, c) __builtin_amdgcn_mfma_f32_16x16x32_bf16((a), (b), (c), 0, 0, 0)

static constexpr int B_SZ = 8;
static constexpr int L = 8192;
static constexpr int H = 1024;
static constexpr int P = 64;
static constexpr int M_TOT = B_SZ * L;        // 65536 rows
static constexpr int S_CH = 256;              // chunk length for scan
static constexpr int NC = L / S_CH;           // 32 chunks per batch

// round-to-nearest-even fp32 -> bf16 bits
__device__ inline ushort_t f2bf(float f) {
    union { float f; unsigned u; } v; v.f = f;
    unsigned r = v.u + 0x7fffu + ((v.u >> 16) & 1u);
    return (ushort_t)(r >> 16);
}

// ---------------------------------------------------------------- params ----
// params[0..63]=dA_r [64..127]=dA_i [128..191]=s_r [192..255]=s_i
// dApow[k*128 + p] = Re(dA^k), [k*128+64+p] = Im(dA^k), k = 0..S_CH
__global__ void params_kernel(const float* __restrict__ A_real,
                              const float* __restrict__ A_imag,
                              const float* __restrict__ inv_dt,
                              float* __restrict__ params,
                              float* __restrict__ dApow) {
    int p = threadIdx.x;  // 64 threads
    float x = inv_dt[p];
    float dt = (x > 20.f) ? x : log1pf(expf(x));
    float ar = A_real[p], ai = A_imag[p];
    float dr = 1.f - 0.5f * dt * ar;
    float di = -0.5f * dt * ai;
    float inv = 1.f / fmaf(dr, dr, di * di);
    float nr = 1.f + 0.5f * dt * ar, ni = 0.5f * dt * ai;
    float dAr = (nr * dr + ni * di) * inv;
    float dAi = (ni * dr - nr * di) * inv;
    params[p]       = dAr;
    params[64 + p]  = dAi;
    params[128 + p] = dt * dr * inv;    // Re(dt/den)
    params[192 + p] = -dt * di * inv;   // Im(dt/den)
    float pr = 1.f, pi = 0.f;
    dApow[p] = 1.f; dApow[64 + p] = 0.f;
    for (int k = 1; k <= S_CH; k++) {
        float npr = pr * dAr - pi * dAi;
        float npi = pr * dAi + pi * dAr;
        pr = npr; pi = npi;
        dApow[k * 128 + p] = pr;
        dApow[k * 128 + 64 + p] = pi;
    }
}

// -------------------------------------------------- build bf16 weights ----
// W1T[n][k], n<64: Re(s_n * B[n][k]);  n>=64: Im(s_{n-64} * B[n-64][k])
// CeffT[h][k], k<64: 2*C_r[h][k];      k>=64: -2*C_i[h][k-64]
__global__ void build_w(const float* __restrict__ Br, const float* __restrict__ Bi,
                        const float* __restrict__ Cr, const float* __restrict__ Ci,
                        const float* __restrict__ params,
                        ushort_t* __restrict__ W1T, ushort_t* __restrict__ CeffT) {
    int t = blockIdx.x * 256 + threadIdx.x;
    if (t < 128 * 1024) {
        int n = t >> 10, k = t & 1023;
        float v;
        if (n < 64) {
            float sr = params[128 + n], si = params[192 + n];
            v = sr * Br[n * 1024 + k] - si * Bi[n * 1024 + k];
        } else {
            int p = n - 64;
            float sr = params[128 + p], si = params[192 + p];
            v = sr * Bi[p * 1024 + k] + si * Br[p * 1024 + k];
        }
        W1T[t] = f2bf(v);
    } else {
        int t2 = t - 128 * 1024;
        int h = t2 >> 7, k = t2 & 127;
        float v = (k < 64) ? 2.f * Cr[h * 64 + k] : -2.f * Ci[h * 64 + (k - 64)];
        CeffT[t2] = f2bf(v);
    }
}

// ------------------------------------------------------------- GEMM 1 ----
// Bu[M_TOT][128] = u[M_TOT][1024] @ W, W[k][n] = W1T[n][k]. 128-row tile/block.
__global__ __launch_bounds__(256) void gemm1(const float* __restrict__ u,
                                             const ushort_t* __restrict__ W1T,
                                             float* __restrict__ Bu) {
    __shared__ ushort_t As[128][40];  // [row][k], pad 32->40 (stride 80B)
    __shared__ ushort_t Bs[128][40];  // [n][k]
    int tid = threadIdx.x;
    int wave = tid >> 6, lane = tid & 63;
    int q = lane >> 4, mn = lane & 15;
    size_t row0 = (size_t)blockIdx.x * 128;
    int r = tid >> 1, half = tid & 1;

    floatx4 acc[2][8] = {};

    for (int kk = 0; kk < 1024; kk += 32) {
        __syncthreads();
        {
            const float4* up = (const float4*)(u + (row0 + r) * 1024 + kk + half * 16);
            float4 f0 = up[0], f1 = up[1], f2 = up[2], f3 = up[3];
            ushort8 t0, t1;
            t0[0] = f2bf(f0.x); t0[1] = f2bf(f0.y); t0[2] = f2bf(f0.z); t0[3] = f2bf(f0.w);
            t0[4] = f2bf(f1.x); t0[5] = f2bf(f1.y); t0[6] = f2bf(f1.z); t0[7] = f2bf(f1.w);
            t1[0] = f2bf(f2.x); t1[1] = f2bf(f2.y); t1[2] = f2bf(f2.z); t1[3] = f2bf(f2.w);
            t1[4] = f2bf(f3.x); t1[5] = f2bf(f3.y); t1[6] = f2bf(f3.z); t1[7] = f2bf(f3.w);
            ushort8* dst = (ushort8*)&As[r][half * 16];
            dst[0] = t0; dst[1] = t1;
            const ushort8* wp = (const ushort8*)(W1T + r * 1024 + kk + half * 16);
            ushort8* db = (ushort8*)&Bs[r][half * 16];
            db[0] = wp[0]; db[1] = wp[1];
        }
        __syncthreads();
        s8v a0 = *(const s8v*)&As[wave * 32 + mn][q * 8];
        s8v a1 = *(const s8v*)&As[wave * 32 + 16 + mn][q * 8];
        #pragma unroll
        for (int j = 0; j < 8; j++) {
            s8v bf = *(const s8v*)&Bs[j * 16 + mn][q * 8];
            acc[0][j] = MFMA16(a0, bf, acc[0][j]);
            acc[1][j] = MFMA16(a1, bf, acc[1][j]);
        }
    }
    #pragma unroll
    for (int i = 0; i < 2; i++)
        #pragma unroll
        for (int j = 0; j < 8; j++)
            #pragma unroll
            for (int reg = 0; reg < 4; reg++) {
                size_t row = row0 + wave * 32 + i * 16 + q * 4 + reg;
                Bu[row * 128 + j * 16 + mn] = acc[i][j][reg];
            }
}

// --------------------------------------------------------- local scan ----
// In-place: Bu becomes h_loc (local prefix, zero initial state per chunk,
// except chunk 0 which folds in dA*h0). Writes per-chunk end state.
__global__ void scan_local(float* __restrict__ Bu, const float* __restrict__ params,
                           const float* __restrict__ h0r, const float* __restrict__ h0i,
                           float* __restrict__ endbuf) {
    int b = blockIdx.x >> 5;
    int c = blockIdx.x & 31;
    int p = threadIdx.x;  // 64
    float dAr = params[p], dAi = params[64 + p];
    size_t base = ((size_t)b * L + (size_t)c * S_CH) * 128 + p;
    float hr = 0.f, hi = 0.f;
    for (int l = 0; l < S_CH; l++) {
        float br = Bu[base + (size_t)l * 128];
        float bi = Bu[base + (size_t)l * 128 + 64];
        if (c == 0 && l == 0) {
            float r0 = h0r[b * 64 + p], i0 = h0i[b * 64 + p];
            br += dAr * r0 - dAi * i0;
            bi += dAr * i0 + dAi * r0;
        }
        float nhr = fmaf(dAr, hr, fmaf(-dAi, hi, br));
        float nhi = fmaf(dAr, hi, fmaf(dAi, hr, bi));
        hr = nhr; hi = nhi;
        Bu[base + (size_t)l * 128] = hr;
        Bu[base + (size_t)l * 128 + 64] = hi;
    }
    endbuf[((size_t)b * NC + c) * 128 + p] = hr;
    endbuf[((size_t)b * NC + c) * 128 + 64 + p] = hi;
}

// --------------------------------------------------------- carry scan ----
// carry[c] = state entering chunk c (i.e. true h at end of chunk c-1).
__global__ void scan_carry(const float* __restrict__ endbuf,
                           const float* __restrict__ dApow,
                           float* __restrict__ carry) {
    int t = blockIdx.x * 64 + threadIdx.x;  // 512 = 8*64
    int b = t >> 6, p = t & 63;
    float aSr = dApow[S_CH * 128 + p], aSi = dApow[S_CH * 128 + 64 + p];
    float cr = 0.f, ci = 0.f;
    for (int c = 0; c < NC; c++) {
        carry[((size_t)b * NC + c) * 128 + p] = cr;
        carry[((size_t)b * NC + c) * 128 + 64 + p] = ci;
        float er = endbuf[((size_t)b * NC + c) * 128 + p];
        float ei = endbuf[((size_t)b * NC + c) * 128 + 64 + p];
        float nr = fmaf(aSr, cr, fmaf(-aSi, ci, er));
        float ni = fmaf(aSr, ci, fmaf(aSi, cr, ei));
        cr = nr; ci = ni;
    }
}

// -------------------------------------------------------------- fixup ----
// hfix[l] = h_loc[l] + dA^((l mod S)+1) * carry[chunk(l)]  -> bf16; also h_last.
__global__ __launch_bounds__(256) void fixup(const float* __restrict__ hloc,
                                             const float* __restrict__ carry,
                                             const float* __restrict__ dApow,
                                             ushort_t* __restrict__ hfix,
                                             float* __restrict__ out_hlast) {
    size_t t = (size_t)blockIdx.x * 256 + threadIdx.x;
    size_t r = t >> 6; int p = (int)(t & 63);
    int b = (int)(r >> 13);
    int l = (int)(r & 8191);
    int c = l >> 8;
    int k = (l & (S_CH - 1)) + 1;
    float pr = dApow[k * 128 + p], pi = dApow[k * 128 + 64 + p];
    float cr = carry[((size_t)b * NC + c) * 128 + p];
    float ci = carry[((size_t)b * NC + c) * 128 + 64 + p];
    float hr = hloc[r * 128 + p] + pr * cr - pi * ci;
    float hi = hloc[r * 128 + 64 + p] + pr * ci + pi * cr;
    hfix[r * 128 + p] = f2bf(hr);
    hfix[r * 128 + 64 + p] = f2bf(hi);
    if (l == L - 1) {
        out_hlast[b * 64 + p] = hr;
        out_hlast[512 + b * 64 + p] = hi;
    }
}

// ------------------------------------------------------------- GEMM 2 ----
// y[row][h] = sum_k hfix[row][k] * CeffT[h][k] + D[h]*u[row][h]
// One block: 128 rows x all 1024 cols (loops 8 col-tiles, restaging B).
__global__ __launch_bounds__(256) void gemm2(const ushort_t* __restrict__ hfix,
                                             const ushort_t* __restrict__ CeffT,
                                             const float* __restrict__ u,
                                             const float* __restrict__ D,
                                             float* __restrict__ y) {
    __shared__ ushort_t As[128][136];  // [row][k] K=128, stride 272B
    __shared__ ushort_t Bs[128][136];  // [n][k]
    int tid = threadIdx.x;
    int wave = tid >> 6, lane = tid & 63;
    int q = lane >> 4, mn = lane & 15;
    size_t row0 = (size_t)blockIdx.x * 128;
    int r = tid >> 1, half = tid & 1;
    {
        const ushort8* src = (const ushort8*)(hfix + (row0 + r) * 128 + half * 64);
        ushort8* dst = (ushort8*)&As[r][half * 64];
        #pragma unroll
        for (int i = 0; i < 8; i++) dst[i] = src[i];
    }
    for (int ct = 0; ct < 8; ct++) {
        __syncthreads();
        {
            const ushort8* src = (const ushort8*)(CeffT + (size_t)(ct * 128 + r) * 128 + half * 64);
            ushort8* dst = (ushort8*)&Bs[r][half * 64];
            #pragma unroll
            for (int i = 0; i < 8; i++) dst[i] = src[i];
        }
        __syncthreads();
        floatx4 acc[2][8] = {};
        #pragma unroll
        for (int kk = 0; kk < 128; kk += 32) {
            s8v a0 = *(const s8v*)&As[wave * 32 + mn][kk + q * 8];
            s8v a1 = *(const s8v*)&As[wave * 32 + 16 + mn][kk + q * 8];
            #pragma unroll
            for (int j = 0; j < 8; j++) {
                s8v bf = *(const s8v*)&Bs[j * 16 + mn][kk + q * 8];
                acc[0][j] = MFMA16(a0, bf, acc[0][j]);
                acc[1][j] = MFMA16(a1, bf, acc[1][j]);
            }
        }
        float dv[8];
        #pragma unroll
        for (int j = 0; j < 8; j++) dv[j] = D[ct * 128 + j * 16 + mn];
        #pragma unroll
        for (int i = 0; i < 2; i++)
            #pragma unroll
            for (int j = 0; j < 8; j++) {
                int col = ct * 128 + j * 16 + mn;
                #pragma unroll
                for (int reg = 0; reg < 4; reg++) {
                    size_t row = row0 + wave * 32 + i * 16 + q * 4 + reg;
                    y[row * 1024 + col] = acc[i][j][reg] + dv[j] * u[row * 1024 + col];
                }
            }
    }
}

// -------------------------------------------------------------- launch ----
extern "C" void kernel_launch(void* const* d_in, const int* in_sizes, int n_in,
                              void* d_out, int out_size, void* d_ws, size_t ws_size,
                              hipStream_t stream) {
    const float* u      = (const float*)d_in[0];
    const float* h_r    = (const float*)d_in[1];
    const float* h_i    = (const float*)d_in[2];
    const float* A_real = (const float*)d_in[3];
    const float* A_imag = (const float*)d_in[4];
    const float* B_real = (const float*)d_in[5];
    const float* B_imag = (const float*)d_in[6];
    const float* C_real = (const float*)d_in[7];
    const float* C_imag = (const float*)d_in[8];
    const float* D      = (const float*)d_in[9];
    const float* inv_dt = (const float*)d_in[10];
    float* out = (float*)d_out;

    // workspace layout (floats from base; all 16B aligned)
    float* wsf       = (float*)d_ws;
    float* P_params  = wsf;                    // 1024 floats reserved
    float* P_dApow   = wsf + 1024;             // 257*128 = 32896, reserve 33024
    float* P_carry   = wsf + 1024 + 33024;     // 8*NC*128 = 32768
    float* P_end     = P_carry + 32768;        // 32768
    ushort_t* P_W1T  = (ushort_t*)(P_end + 32768);      // 128*1024 bf16
    ushort_t* P_Ceff = P_W1T + 128 * 1024;              // 1024*128 bf16
    float* P_Bu      = (float*)(P_Ceff + 1024 * 128);   // 65536*128 f32 (33.5MB)
    ushort_t* P_hfix = (ushort_t*)(P_Bu + (size_t)M_TOT * 128);  // 65536*128 bf16

    params_kernel<<<1, 64, 0, stream>>>(A_real, A_imag, inv_dt, P_params, P_dApow);
    build_w<<<1024, 256, 0, stream>>>(B_real, B_imag, C_real, C_imag, P_params, P_W1T, P_Ceff);
    gemm1<<<M_TOT / 128, 256, 0, stream>>>(u, P_W1T, P_Bu);
    scan_local<<<B_SZ * NC, 64, 0, stream>>>(P_Bu, P_params, h_r, h_i, P_end);
    scan_carry<<<8, 64, 0, stream>>>(P_end, P_dApow, P_carry);
    fixup<<<(M_TOT * 64) / 256, 256, 0, stream>>>(P_Bu, P_carry, P_dApow, P_hfix,
                                                  out + (size_t)M_TOT * H);
    gemm2<<<M_TOT / 128, 256, 0, stream>>>(P_hfix, P_Ceff, u, D, out);
}